// Round 1
// 420.126 us; speedup vs baseline: 1.0152x; 1.0152x over previous
//
#include <hip/hip_runtime.h>
#include <math.h>

#define ROWS 16384
#define DD   4096
#define EE   64
#define EPSF 1e-10f

#define BM     128               // rows per block
#define KT     32                // k per tile
#define KSPLIT 4
#define KRANGE (DD / KSPLIT)     // 1024
#define NKT    (KRANGE / KT)     // 32
#define WTILE  12288             // bytes per pre-split w k-tile (3*4*64*16)

typedef __attribute__((ext_vector_type(8))) short short8;   // 8 bf16
typedef __attribute__((ext_vector_type(4))) float f32x4;    // MFMA C/D
typedef __attribute__((ext_vector_type(4))) unsigned u32x4; // packed bf16x8

// RNE 3-level bf16 split of 8 floats, pair-packed into 3x (4 dwords).
// Bit-identical to rne_bf16-based split3 of the previous version.
__device__ __forceinline__ void split3x8(const float f[8], u32x4& w0,
                                         u32x4& w1, u32x4& w2) {
#pragma unroll
  for (int i = 0; i < 4; ++i) {
    float fa = f[2 * i], fb = f[2 * i + 1];
    unsigned ua = __float_as_uint(fa), ub = __float_as_uint(fb);
    unsigned ra = ua + 0x7fffu + ((ua >> 16) & 1u);
    unsigned rb = ub + 0x7fffu + ((ub >> 16) & 1u);
    w0[i] = (rb & 0xffff0000u) | (ra >> 16);
    fa -= __uint_as_float(ra & 0xffff0000u);
    fb -= __uint_as_float(rb & 0xffff0000u);
    ua = __float_as_uint(fa); ub = __float_as_uint(fb);
    ra = ua + 0x7fffu + ((ua >> 16) & 1u);
    rb = ub + 0x7fffu + ((ub >> 16) & 1u);
    w1[i] = (rb & 0xffff0000u) | (ra >> 16);
    fa -= __uint_as_float(ra & 0xffff0000u);
    fb -= __uint_as_float(rb & 0xffff0000u);
    ua = __float_as_uint(fa); ub = __float_as_uint(fb);
    ra = ua + 0x7fffu + ((ua >> 16) & 1u);
    rb = ub + 0x7fffu + ((ub >> 16) & 1u);
    w2[i] = (rb & 0xffff0000u) | (ra >> 16);
  }
}

__device__ __forceinline__ void dma16(const void* g, void* l) {
  __builtin_amdgcn_global_load_lds(
      (const __attribute__((address_space(1))) unsigned int*)g,
      (__attribute__((address_space(3))) unsigned int*)l, 16, 0, 0);
}

// ---------------------------------------------------------------------------
// One-time w pre-split into MFMA-B-fragment-ready layout:
//   wsp[kt][part p][et][lp][8 bf16]; lp = k_octet*16 + (e&15), et = e>>4.
// Read in k_gemm as: lane reads [p][et][lane][0..7] (16B per lane, linear).
// ---------------------------------------------------------------------------
__global__ __launch_bounds__(256) void k_wsplit(const float* __restrict__ wr,
                                                unsigned char* __restrict__ out) {
  const int kt = blockIdx.x;  // global k-tile 0..127
  const int t = threadIdx.x;
  const int lane = t & 63, wv = t >> 6;
  float f[8];
  const float* wp = wr + (size_t)(kt * 32 + wv * 8) * EE + lane;
#pragma unroll
  for (int j = 0; j < 8; ++j) f[j] = wp[(size_t)j * EE];
  u32x4 w0, w1, w2;
  split3x8(f, w0, w1, w2);
  const int et = lane >> 4;
  const int lp = wv * 16 + (lane & 15);
  unsigned char* base = out + (size_t)kt * WTILE + et * 1024 + lp * 16;
  *(u32x4*)(base + 0 * 4096) = w0;
  *(u32x4*)(base + 1 * 4096) = w1;
  *(u32x4*)(base + 2 * 4096) = w2;
}

// ---------------------------------------------------------------------------
// Router GEMM, 3-way-split bf16 MFMA (6 terms ~ fp32 precision).
// 512 blocks x 256 thr: 128 rows x 64 experts x 1024 k, KSPLIT=4 via atomics.
// A-operand: direct per-lane global loads (h reuse = 1, no LDS staging).
// B-operand: pre-split frags DMA'd global->LDS (global_load_lds, dbuf).
// ONE barrier per kt; prefetch issued after the barrier so the implicit
// vmcnt(0) drain lands a full compute phase later.
// ---------------------------------------------------------------------------
__global__ __launch_bounds__(256) void k_gemm(
    const float* __restrict__ h, const unsigned char* __restrict__ wsp,
    float* __restrict__ logits) {
  __shared__ alignas(16) unsigned char wsf[2][WTILE];  // 24 KB double-buffer

  const int t = threadIdx.x;
  const int lane = t & 63;
  const int wv = t >> 6;
  const int row0 = (blockIdx.x >> 2) * BM;
  const int kb0 = (blockIdx.x & 3) * KRANGE;

  f32x4 acc[2][4] = {};

  // per-lane A addresses: row = row0 + wv*32 + mt*16 + (lane&15),
  //                       k   = kb0 + (lane>>4)*8 + j
  const int rl0 = row0 + wv * 32 + (lane & 15);
  const int kcol = kb0 + (lane >> 4) * 8;
  const float* ap0 = h + (size_t)rl0 * DD + kcol;        // mt=0
  const float* ap1 = ap0 + (size_t)16 * DD;              // mt=1

  const unsigned char* wsrc = wsp + (size_t)(kb0 / KT) * WTILE;
  const int chunkoff = wv * 1024 + lane * 16;            // + c*4096

  float4 cur[4], nxt[4];
  // prologue: tile 0 (A to regs, B via DMA to LDS buf 0)
  cur[0] = *(const float4*)(ap0);
  cur[1] = *(const float4*)(ap0 + 4);
  cur[2] = *(const float4*)(ap1);
  cur[3] = *(const float4*)(ap1 + 4);
#pragma unroll
  for (int c = 0; c < 3; ++c)
    dma16(wsrc + c * 4096 + chunkoff, &wsf[0][c * 4096 + chunkoff]);

  for (int kt = 0; kt < NKT; ++kt) {
    const int buf = kt & 1;
    // drain this-tile DMA (and any residual A loads), then sync
    asm volatile("s_waitcnt vmcnt(0)" ::: "memory");
    __syncthreads();

    // issue next-tile prefetch NOW; it has the whole compute phase to land
    if (kt + 1 < NKT) {
      const float* p0 = ap0 + (size_t)(kt + 1) * KT;
      const float* p1 = ap1 + (size_t)(kt + 1) * KT;
      nxt[0] = *(const float4*)(p0);
      nxt[1] = *(const float4*)(p0 + 4);
      nxt[2] = *(const float4*)(p1);
      nxt[3] = *(const float4*)(p1 + 4);
      const unsigned char* ws = wsrc + (size_t)(kt + 1) * WTILE;
#pragma unroll
      for (int c = 0; c < 3; ++c)
        dma16(ws + c * 4096 + chunkoff, &wsf[buf ^ 1][c * 4096 + chunkoff]);
    }

    // B fragments: 3 parts x 4 e-tiles, 16B/lane linear (2-way bank = free)
    short8 bf[3][4];
#pragma unroll
    for (int p = 0; p < 3; ++p)
#pragma unroll
      for (int et = 0; et < 4; ++et)
        bf[p][et] =
            *(const short8*)&wsf[buf][p * 4096 + et * 1024 + lane * 16];

#pragma unroll
    for (int mt = 0; mt < 2; ++mt) {
      const float4 a0 = cur[mt * 2], a1 = cur[mt * 2 + 1];
      const float af[8] = {a0.x, a0.y, a0.z, a0.w, a1.x, a1.y, a1.z, a1.w};
      u32x4 q0, q1, q2;
      split3x8(af, q0, q1, q2);
      const short8 ah0 = __builtin_bit_cast(short8, q0);
      const short8 ah1 = __builtin_bit_cast(short8, q1);
      const short8 ah2 = __builtin_bit_cast(short8, q2);
#pragma unroll
      for (int et = 0; et < 4; ++et) {
        f32x4 c = acc[mt][et];
        c = __builtin_amdgcn_mfma_f32_16x16x32_bf16(ah0, bf[0][et], c, 0, 0, 0);
        c = __builtin_amdgcn_mfma_f32_16x16x32_bf16(ah0, bf[1][et], c, 0, 0, 0);
        c = __builtin_amdgcn_mfma_f32_16x16x32_bf16(ah1, bf[0][et], c, 0, 0, 0);
        c = __builtin_amdgcn_mfma_f32_16x16x32_bf16(ah0, bf[2][et], c, 0, 0, 0);
        c = __builtin_amdgcn_mfma_f32_16x16x32_bf16(ah1, bf[1][et], c, 0, 0, 0);
        c = __builtin_amdgcn_mfma_f32_16x16x32_bf16(ah2, bf[0][et], c, 0, 0, 0);
        acc[mt][et] = c;
      }
    }

    if (kt + 1 < NKT) {
#pragma unroll
      for (int i = 0; i < 4; ++i) cur[i] = nxt[i];
    }
  }

  // epilogue: K-split partial accumulate (C layout: col=lane&15, row=quad*4+r)
#pragma unroll
  for (int mt = 0; mt < 2; ++mt) {
    const int rbase = row0 + wv * 32 + mt * 16 + (lane >> 4) * 4;
    const int col = lane & 15;
#pragma unroll
    for (int et = 0; et < 4; ++et) {
#pragma unroll
      for (int r = 0; r < 4; ++r)
        atomicAdd(&logits[(size_t)(rbase + r) * EE + et * 16 + col],
                  acc[mt][et][r]);
    }
  }
}

// ---------------------------------------------------------------------------
// softmax + expert-load accumulation. 256 blocks x 4 waves; wave = 16 rows,
// lane = expert. Per-lane register accumulation -> 64 atomics per block.
// ---------------------------------------------------------------------------
__global__ __launch_bounds__(256) void k_softload(
    const float* __restrict__ logits, float* __restrict__ g_load) {
  __shared__ float red[4][64];
  const int lane = threadIdx.x & 63;
  const int wv = threadIdx.x >> 6;
  float accp = 0.f;
#pragma unroll 4
  for (int i = 0; i < 16; ++i) {
    int row = blockIdx.x * 64 + wv * 16 + i;
    float x = logits[(size_t)row * EE + lane];
    float m = x;
#pragma unroll
    for (int off = 32; off > 0; off >>= 1) m = fmaxf(m, __shfl_xor(m, off, 64));
    float p = __expf(x - m);
    float s = p;
#pragma unroll
    for (int off = 32; off > 0; off >>= 1) s += __shfl_xor(s, off, 64);
    accp += p / s;
  }
  red[wv][lane] = accp;
  __syncthreads();
  if (wv == 0) {
    float s = red[0][lane] + red[1][lane] + red[2][lane] + red[3][lane];
    atomicAdd(&g_load[lane], s);
  }
}

// ---------------------------------------------------------------------------
// penalty (recomputed per wave: 64-wide reduce + logf, trivially cheap)
// + adjusted logits + top-2. One row per wave.
// ---------------------------------------------------------------------------
__global__ __launch_bounds__(256) void k_top2(float* __restrict__ logits,
                                              const float* __restrict__ g_load,
                                              float* __restrict__ idx_out) {
  int t = threadIdx.x;
  int lane = t & 63;
  int wv = t >> 6;
  int row = blockIdx.x * 4 + wv;

  float v0 = g_load[lane];
  float s0 = v0;
#pragma unroll
  for (int off = 32; off > 0; off >>= 1) s0 += __shfl_xor(s0, off, 64);
  float lp = logf(v0 / (s0 * (1.f / 64.f) + EPSF) + EPSF);

  size_t base = (size_t)row * EE;
  float a = logits[base + lane] - lp;
  logits[base + lane] = a;

  float v = a;
  int idx = lane;
#pragma unroll
  for (int off = 32; off > 0; off >>= 1) {
    float ov = __shfl_xor(v, off, 64);
    int oi = __shfl_xor(idx, off, 64);
    if (ov > v || (ov == v && oi < idx)) { v = ov; idx = oi; }
  }
  int i1 = idx;

  float a2 = (lane == i1) ? -INFINITY : a;
  v = a2;
  idx = lane;
#pragma unroll
  for (int off = 32; off > 0; off >>= 1) {
    float ov = __shfl_xor(v, off, 64);
    int oi = __shfl_xor(idx, off, 64);
    if (ov > v || (ov == v && oi < idx)) { v = ov; idx = oi; }
  }
  int i2 = idx;

  if (lane == 0) {
    idx_out[(size_t)row * 2 + 0] = (float)i1;
    idx_out[(size_t)row * 2 + 1] = (float)i2;
  }
}

// ---------------------------------------------------------------------------
extern "C" void kernel_launch(void* const* d_in, const int* in_sizes, int n_in,
                              void* d_out, int out_size, void* d_ws,
                              size_t ws_size, hipStream_t stream) {
  const float* h = (const float*)d_in[0];   // [4,4096,4096]
  const float* wr = (const float*)d_in[1];  // [4096,64]
  float* out = (float*)d_out;
  float* logits = out;                          // ROWS*EE
  float* idx_out = out + (size_t)ROWS * EE;     // ROWS*2
  float* g_load = (float*)d_ws;                 // 64 floats
  unsigned char* wsp = (unsigned char*)d_ws + 512;  // 1.5 MiB pre-split w

  hipMemsetAsync(d_out, 0, (size_t)ROWS * EE * sizeof(float), stream);
  hipMemsetAsync(d_ws, 0, 512, stream);
  k_wsplit<<<DD / KT, 256, 0, stream>>>(wr, wsp);
  k_gemm<<<(ROWS / BM) * KSPLIT, 256, 0, stream>>>(h, wsp, logits);
  k_softload<<<ROWS / 64, 256, 0, stream>>>(logits, g_load);
  k_top2<<<ROWS / 4, 256, 0, stream>>>(logits, g_load, idx_out);
}